// Round 9
// baseline (547.174 us; speedup 1.0000x reference)
//
#include <hip/hip_runtime.h>
#include <math.h>

#define NB 4096
#define NN 256
#define NF 16
#define NK 64
#define DIN 19
#define DM 128
#define DFF 256

using short8  = __attribute__((ext_vector_type(8))) short;
using short4v = __attribute__((ext_vector_type(4))) short;
using f32x4   = __attribute__((ext_vector_type(4))) float;

__device__ inline f32x4 mfma32(short8 a, short8 b, f32x4 c) {
    return __builtin_amdgcn_mfma_f32_16x16x32_bf16(a, b, c, 0, 0, 0);
}
__device__ inline f32x4 mfma16(short4v a, short4v b, f32x4 c) {
    return __builtin_amdgcn_mfma_f32_16x16x16bf16_1k(a, b, c, 0, 0, 0);
}

__device__ inline ushort f2bf(float f) {
    unsigned u = __float_as_uint(f);
    return (ushort)((u + 0x7fffu + ((u >> 16) & 1u)) >> 16);
}
__device__ inline float bf2f(ushort h) {
    return __uint_as_float(((unsigned)h) << 16);
}

// ---- pre-kernel: convert + PERMUTE weights so fragment reads are contiguous ----
__global__ void convert_weights(const float* __restrict__ W_emb,
                                const float* __restrict__ b_emb,
                                const float* __restrict__ W1,
                                const float* __restrict__ W2,
                                ushort* __restrict__ Wembc,
                                ushort* __restrict__ W1c,
                                ushort* __restrict__ W2c) {
    const int i = blockIdx.x * 256 + threadIdx.x;   // 0..32767
    if (i < 4096) {
        const int j = i & 7, s = i >> 3;
        const int nt = s >> 6, lane = s & 63;
        const int n = nt*16 + (lane & 15);
        const int k = (lane >> 4)*8 + j;
        float v = (k < DIN) ? W_emb[n*DIN + k] : (k == 31 ? b_emb[n] : 0.0f);
        Wembc[i] = f2bf(v);
    }
    if (i < 32768) {
        const int e = i & 3, s = i >> 2;
        const int grp = s >> 6, lane = s & 63;
        const int lr = lane & 15, lg = lane >> 4;
        const int n1 = (grp >> 3)*16 + lr;
        const int k1 = (grp & 7)*16 + lg*4 + e;
        W1c[i] = f2bf(W1[n1*DM + k1]);
        const int n2 = (grp >> 4)*16 + lr;
        const int k2 = (grp & 15)*16 + lg*4 + e;
        W2c[i] = f2bf(W2[n2*DFF + k2]);
    }
}

// ---- kernel 1: top-K select + feature build ----
__global__ __launch_bounds__(256) void select_kernel(
    const float* __restrict__ x, const int* __restrict__ idxs,
    const float* __restrict__ origin, const float* __restrict__ direction,
    const float* __restrict__ norm_count, const float* __restrict__ norm_mean,
    const float* __restrict__ norm_sqsum,
    ushort* __restrict__ xnB, float* __restrict__ outrel, float* __restrict__ outmask)
{
    __shared__ unsigned long long s_keys[NN];
    const int b = blockIdx.x;
    const int t = threadIdx.x;

    const float dirx = direction[b*2+0], diry = direction[b*2+1];
    const float ang = -atan2f(diry, dirx);
    const float cr = cosf(ang), sr = sinf(ang);
    const float ox = origin[b*2+0], oy = origin[b*2+1];

    {
        const int j = idxs[b*NN + t];
        const float4 xr = *reinterpret_cast<const float4*>(x + (size_t)j*NF);
        const float dx = xr.x - ox, dy = xr.y - oy;
        const float r0 = cr*dx - sr*dy;
        const float r1 = sr*dx + cr*dy;
        const float dist = sqrtf(r0*r0 + r1*r1);
        const float key = -dist - ((xr.z == 0.0f) ? 1e8f : 0.0f);
        unsigned u = __float_as_uint(key);
        u = (u & 0x80000000u) ? ~u : (u | 0x80000000u);
        s_keys[t] = ((unsigned long long)(~u) << 32) | (unsigned)t;
    }
    __syncthreads();

    for (int sz = 2; sz <= NN; sz <<= 1) {
        for (int st = sz >> 1; st > 0; st >>= 1) {
            const int ixj = t ^ st;
            if (ixj > t) {
                const unsigned long long a = s_keys[t];
                const unsigned long long c = s_keys[ixj];
                const bool up = ((t & sz) == 0);
                if ((a > c) == up) { s_keys[t] = c; s_keys[ixj] = a; }
            }
            __syncthreads();
        }
    }

    if (t < NK) {
        const int p = (int)(s_keys[t] & 0xFFFFFFFFull);
        const int j = idxs[b*NN + p];
        const float4* xrow = reinterpret_cast<const float4*>(x + (size_t)j*NF);
        const float4 a0 = xrow[0], a1 = xrow[1], a2 = xrow[2], a3 = xrow[3];
        float xc[DIN];
        xc[0]=a0.x; xc[1]=a0.y; xc[2]=a0.z; xc[3]=a0.w;
        xc[4]=a1.x; xc[5]=a1.y; xc[6]=a1.z; xc[7]=a1.w;
        xc[8]=a2.x; xc[9]=a2.y; xc[10]=a2.z; xc[11]=a2.w;
        xc[12]=a3.x; xc[13]=a3.y; xc[14]=a3.z; xc[15]=a3.w;
        const float dx = xc[0]-ox, dy = xc[1]-oy;
        const float r0 = cr*dx - sr*dy;
        const float r1 = sr*dx + cr*dy;
        const float dist = sqrtf(r0*r0 + r1*r1);
        const float inv = 1.0f / (dist + 1e-8f);
        xc[16] = r0*inv; xc[17] = r1*inv; xc[18] = sqrtf(dist);
        const float cnt = norm_count[0];
        union { ushort us[32]; int4 v4[4]; } u;
        #pragma unroll
        for (int f = 0; f < DIN; ++f) {
            float sd = sqrtf(norm_sqsum[f] / (cnt - 1.0f));
            sd = (sd == 0.0f) ? 1.0f : sd;
            float v = (xc[f] - norm_mean[f]) / sd;
            v = fminf(fmaxf(v, -5.0f), 5.0f);
            u.us[f] = f2bf(v);
        }
        #pragma unroll
        for (int f = DIN; f < 31; ++f) u.us[f] = 0;
        u.us[31] = 0x3F80;   // 1.0 bf16 -> bias column
        int4* dst = reinterpret_cast<int4*>(xnB + ((size_t)b*NK + t)*32);
        dst[0] = u.v4[0]; dst[1] = u.v4[1]; dst[2] = u.v4[2]; dst[3] = u.v4[3];
        const bool msk = (xc[2] == 0.0f);
        outrel[((size_t)b*NK + t)*2 + 0] = r0;
        outrel[((size_t)b*NK + t)*2 + 1] = r1;
        outmask[(size_t)b*NK + t] = msk ? 1.0f : 0.0f;
    }
}

// ---- kernel 2: all-register transposed MLP, SINGLE batch per iteration ----
// R8 post-mortem: 2-batch ILP needed ~250+ live regs -> arch-VGPR saturated at
// 256 -> in-loop spill/fill = the 460MB phantom FETCH. Single-batch halves the
// working set (~140 regs) -> no spill.
__global__ __launch_bounds__(256, 1) void mlp_kernel(
    const float* __restrict__ b1, const float* __restrict__ b2,
    const float* __restrict__ ln1g, const float* __restrict__ ln1b,
    const float* __restrict__ ln2g, const float* __restrict__ ln2b,
    const ushort* __restrict__ Wembc, const ushort* __restrict__ W1c,
    const ushort* __restrict__ W2c, const ushort* __restrict__ xnB,
    const float* __restrict__ outmask, float* __restrict__ out)
{
    __shared__ __align__(16) ushort s_w1[32768];     // 64 KB
    __shared__ __align__(16) ushort s_w2[32768];     // 64 KB -> 128 KB, 1 block/CU

    const int t = threadIdx.x;
    {
        const int4* g1 = (const int4*)W1c;  int4* d1 = (int4*)s_w1;
        const int4* g2 = (const int4*)W2c;  int4* d2 = (int4*)s_w2;
        #pragma unroll
        for (int j = 0; j < 16; ++j) { d1[j*256 + t] = g1[j*256 + t];
                                       d2[j*256 + t] = g2[j*256 + t]; }
    }
    __syncthreads();

    const int wave = t >> 6, lane = t & 63;
    const int lr = lane & 15, lg = lane >> 4;
    const int m0 = wave * 16;

    // Wemb fragments hoisted to registers (L2-resident, read once)
    short8 wembR[8];
    #pragma unroll
    for (int nt = 0; nt < 8; ++nt)
        wembR[nt] = *(const short8*)(Wembc + nt*512 + lane*8);

    const f32x4 zero = {0.f, 0.f, 0.f, 0.f};

    for (int it = 0; it < 16; ++it) {
        const int b = blockIdx.x*16 + it;

        // ---- G1 (swapped): h1T = Wemb @ xn^T ; bias folded via col31 ----
        const short8 xA = *(const short8*)(xnB + ((size_t)b*NK + m0 + lr)*32 + 8*lg);
        f32x4 h1[8];
        #pragma unroll
        for (int nt = 0; nt < 8; ++nt)
            h1[nt] = mfma32(wembR[nt], xA, zero);

        // ---- LN1: relu + stats over n (lane-local 32 + 2 shuffles) ----
        float ps = 0.f, pq = 0.f;
        #pragma unroll
        for (int nt = 0; nt < 8; ++nt)
            #pragma unroll
            for (int r = 0; r < 4; ++r) {
                float a = fmaxf(h1[nt][r], 0.f); h1[nt][r] = a; ps += a; pq += a*a;
            }
        #pragma unroll
        for (int m = 16; m <= 32; m <<= 1) {
            ps += __shfl_xor(ps, m, 64); pq += __shfl_xor(pq, m, 64);
        }
        const float mu = ps*(1.f/128.f);
        const float rs = rsqrtf(pq*(1.f/128.f) - mu*mu + 1e-5f);

        // ---- affine + pack to bf16 (these ARE the G2 B-fragments) ----
        short4v h1p[8];
        #pragma unroll
        for (int nt = 0; nt < 8; ++nt) {
            const float4 g = *(const float4*)(ln1g + nt*16 + 4*lg);
            const float4 bb = *(const float4*)(ln1b + nt*16 + 4*lg);
            const float gr[4] = {g.x, g.y, g.z, g.w};
            const float br[4] = {bb.x, bb.y, bb.z, bb.w};
            #pragma unroll
            for (int r = 0; r < 4; ++r)
                h1p[nt][r] = (short)f2bf((h1[nt][r]-mu)*rs*gr[r] + br[r]);
        }

        // ---- G2 (chunks of 4 n2-tiles) feeding G3 accumulation ----
        f32x4 acc3[8];
        #pragma unroll
        for (int nt3 = 0; nt3 < 8; ++nt3) {
            const float4 bb = *(const float4*)(b2 + nt3*16 + 4*lg);
            acc3[nt3] = f32x4{bb.x, bb.y, bb.z, bb.w};
        }
        #pragma unroll
        for (int ck = 0; ck < 4; ++ck) {
            short4v h2p[4];
            #pragma unroll
            for (int j = 0; j < 4; ++j) {
                const int nt2 = ck*4 + j;
                const float4 bb = *(const float4*)(b1 + nt2*16 + 4*lg);
                f32x4 a2 = f32x4{bb.x, bb.y, bb.z, bb.w};
                #pragma unroll
                for (int kt = 0; kt < 8; ++kt) {
                    const short4v w = *(const short4v*)(s_w1 + (nt2*8 + kt)*256 + lane*4);
                    a2 = mfma16(w, h1p[kt], a2);
                }
                #pragma unroll
                for (int r = 0; r < 4; ++r)
                    h2p[j][r] = (short)f2bf(fmaxf(a2[r], 0.f));
            }
            #pragma unroll
            for (int nt3 = 0; nt3 < 8; ++nt3)
                #pragma unroll
                for (int j = 0; j < 4; ++j) {
                    const short4v w = *(const short4v*)(s_w2 + (nt3*16 + ck*4 + j)*256 + lane*4);
                    acc3[nt3] = mfma16(w, h2p[j], acc3[nt3]);
                }
        }

        // ---- residual + LN2 stats (T layout) ----
        const float keep = 1.f - outmask[(size_t)b*NK + m0 + lr];
        ps = 0.f; pq = 0.f;
        #pragma unroll
        for (int nt = 0; nt < 8; ++nt)
            #pragma unroll
            for (int r = 0; r < 4; ++r) {
                const float q = bf2f((ushort)h1p[nt][r]) + fmaxf(acc3[nt][r], 0.f);
                acc3[nt][r] = q; ps += q; pq += q*q;
            }
        #pragma unroll
        for (int m = 16; m <= 32; m <<= 1) {
            ps += __shfl_xor(ps, m, 64); pq += __shfl_xor(pq, m, 64);
        }
        const float m2 = ps*(1.f/128.f);
        const float r2 = rsqrtf(pq*(1.f/128.f) - m2*m2 + 1e-5f);

        // ---- LN2 affine + mask + store (full 64B line per (row,nt)) ----
        #pragma unroll
        for (int nt = 0; nt < 8; ++nt) {
            const float4 g = *(const float4*)(ln2g + nt*16 + 4*lg);
            const float4 bb = *(const float4*)(ln2b + nt*16 + 4*lg);
            float4 o;
            o.x = ((acc3[nt][0]-m2)*r2*g.x + bb.x)*keep;
            o.y = ((acc3[nt][1]-m2)*r2*g.y + bb.y)*keep;
            o.z = ((acc3[nt][2]-m2)*r2*g.z + bb.z)*keep;
            o.w = ((acc3[nt][3]-m2)*r2*g.w + bb.w)*keep;
            *(float4*)(out + ((size_t)b*NK + m0 + lr)*DM + nt*16 + 4*lg) = o;
        }
    }
}

extern "C" void kernel_launch(void* const* d_in, const int* in_sizes, int n_in,
                              void* d_out, int out_size, void* d_ws, size_t ws_size,
                              hipStream_t stream) {
    const float* x        = (const float*)d_in[0];
    const int*   idxs     = (const int*)  d_in[1];
    const float* origin   = (const float*)d_in[2];
    const float* direction= (const float*)d_in[3];
    const float* ncount   = (const float*)d_in[4];
    const float* nmean    = (const float*)d_in[5];
    const float* nsq      = (const float*)d_in[6];
    const float* W_emb    = (const float*)d_in[7];
    const float* b_emb    = (const float*)d_in[8];
    const float* ln1g     = (const float*)d_in[9];
    const float* ln1b     = (const float*)d_in[10];
    const float* W1       = (const float*)d_in[11];
    const float* b1       = (const float*)d_in[12];
    const float* W2       = (const float*)d_in[13];
    const float* b2       = (const float*)d_in[14];
    const float* ln2g     = (const float*)d_in[15];
    const float* ln2b     = (const float*)d_in[16];

    float* out     = (float*)d_out;
    float* outrel  = out    + (size_t)NB*NK*DM;
    float* outmask = outrel + (size_t)NB*NK*2;

    ushort* Wembc = (ushort*)d_ws;              // 4096
    ushort* W1c   = Wembc + 4096;               // 32768
    ushort* W2c   = W1c   + 32768;              // 32768
    ushort* xnB   = W2c   + 32768;              // 4096*64*32 (16 MB)

    convert_weights<<<128, 256, 0, stream>>>(W_emb, b_emb, W1, W2, Wembc, W1c, W2c);
    select_kernel<<<NB, 256, 0, stream>>>(x, idxs, origin, direction, ncount,
        nmean, nsq, xnB, outrel, outmask);
    mlp_kernel<<<256, 256, 0, stream>>>(b1, b2, ln1g, ln1b, ln2g, ln2b,
        Wembc, W1c, W2c, xnB, outmask, out);
}

// Round 11
// 355.756 us; speedup vs baseline: 1.5381x; 1.5381x over previous
//
#include <hip/hip_runtime.h>
#include <math.h>

#define NB 4096
#define NN 256
#define NF 16
#define NK 64
#define DIN 19
#define DM 128
#define DFF 256

using short8  = __attribute__((ext_vector_type(8))) short;
using short4v = __attribute__((ext_vector_type(4))) short;
using f32x4   = __attribute__((ext_vector_type(4))) float;

__device__ inline f32x4 mfma32(short8 a, short8 b, f32x4 c) {
    return __builtin_amdgcn_mfma_f32_16x16x32_bf16(a, b, c, 0, 0, 0);
}
__device__ inline f32x4 mfma16(short4v a, short4v b, f32x4 c) {
    return __builtin_amdgcn_mfma_f32_16x16x16bf16_1k(a, b, c, 0, 0, 0);
}

__device__ inline ushort f2bf(float f) {
    unsigned u = __float_as_uint(f);
    return (ushort)((u + 0x7fffu + ((u >> 16) & 1u)) >> 16);
}
__device__ inline float bf2f(ushort h) {
    return __uint_as_float(((unsigned)h) << 16);
}

// ---- pre-kernel: convert + PERMUTE weights so fragment reads are contiguous ----
__global__ void convert_weights(const float* __restrict__ W_emb,
                                const float* __restrict__ b_emb,
                                const float* __restrict__ W1,
                                const float* __restrict__ W2,
                                ushort* __restrict__ Wembc,
                                ushort* __restrict__ W1c,
                                ushort* __restrict__ W2c) {
    const int i = blockIdx.x * 256 + threadIdx.x;   // 0..32767
    if (i < 4096) {
        const int j = i & 7, s = i >> 3;
        const int nt = s >> 6, lane = s & 63;
        const int n = nt*16 + (lane & 15);
        const int k = (lane >> 4)*8 + j;
        float v = (k < DIN) ? W_emb[n*DIN + k] : (k == 31 ? b_emb[n] : 0.0f);
        Wembc[i] = f2bf(v);
    }
    if (i < 32768) {
        const int e = i & 3, s = i >> 2;
        const int grp = s >> 6, lane = s & 63;
        const int lr = lane & 15, lg = lane >> 4;
        const int n1 = (grp >> 3)*16 + lr;
        const int k1 = (grp & 7)*16 + lg*4 + e;
        W1c[i] = f2bf(W1[n1*DM + k1]);
        const int n2 = (grp >> 4)*16 + lr;
        const int k2 = (grp & 15)*16 + lg*4 + e;
        W2c[i] = f2bf(W2[n2*DFF + k2]);
    }
}

// ---- kernel 1: top-K select + feature build ----
__global__ __launch_bounds__(256) void select_kernel(
    const float* __restrict__ x, const int* __restrict__ idxs,
    const float* __restrict__ origin, const float* __restrict__ direction,
    const float* __restrict__ norm_count, const float* __restrict__ norm_mean,
    const float* __restrict__ norm_sqsum,
    ushort* __restrict__ xnB, float* __restrict__ outrel, float* __restrict__ outmask)
{
    __shared__ unsigned long long s_keys[NN];
    const int b = blockIdx.x;
    const int t = threadIdx.x;

    const float dirx = direction[b*2+0], diry = direction[b*2+1];
    const float ang = -atan2f(diry, dirx);
    const float cr = cosf(ang), sr = sinf(ang);
    const float ox = origin[b*2+0], oy = origin[b*2+1];

    {
        const int j = idxs[b*NN + t];
        const float4 xr = *reinterpret_cast<const float4*>(x + (size_t)j*NF);
        const float dx = xr.x - ox, dy = xr.y - oy;
        const float r0 = cr*dx - sr*dy;
        const float r1 = sr*dx + cr*dy;
        const float dist = sqrtf(r0*r0 + r1*r1);
        const float key = -dist - ((xr.z == 0.0f) ? 1e8f : 0.0f);
        unsigned u = __float_as_uint(key);
        u = (u & 0x80000000u) ? ~u : (u | 0x80000000u);
        s_keys[t] = ((unsigned long long)(~u) << 32) | (unsigned)t;
    }
    __syncthreads();

    for (int sz = 2; sz <= NN; sz <<= 1) {
        for (int st = sz >> 1; st > 0; st >>= 1) {
            const int ixj = t ^ st;
            if (ixj > t) {
                const unsigned long long a = s_keys[t];
                const unsigned long long c = s_keys[ixj];
                const bool up = ((t & sz) == 0);
                if ((a > c) == up) { s_keys[t] = c; s_keys[ixj] = a; }
            }
            __syncthreads();
        }
    }

    if (t < NK) {
        const int p = (int)(s_keys[t] & 0xFFFFFFFFull);
        const int j = idxs[b*NN + p];
        const float4* xrow = reinterpret_cast<const float4*>(x + (size_t)j*NF);
        const float4 a0 = xrow[0], a1 = xrow[1], a2 = xrow[2], a3 = xrow[3];
        float xc[DIN];
        xc[0]=a0.x; xc[1]=a0.y; xc[2]=a0.z; xc[3]=a0.w;
        xc[4]=a1.x; xc[5]=a1.y; xc[6]=a1.z; xc[7]=a1.w;
        xc[8]=a2.x; xc[9]=a2.y; xc[10]=a2.z; xc[11]=a2.w;
        xc[12]=a3.x; xc[13]=a3.y; xc[14]=a3.z; xc[15]=a3.w;
        const float dx = xc[0]-ox, dy = xc[1]-oy;
        const float r0 = cr*dx - sr*dy;
        const float r1 = sr*dx + cr*dy;
        const float dist = sqrtf(r0*r0 + r1*r1);
        const float inv = 1.0f / (dist + 1e-8f);
        xc[16] = r0*inv; xc[17] = r1*inv; xc[18] = sqrtf(dist);
        const float cnt = norm_count[0];
        union { ushort us[32]; int4 v4[4]; } u;
        #pragma unroll
        for (int f = 0; f < DIN; ++f) {
            float sd = sqrtf(norm_sqsum[f] / (cnt - 1.0f));
            sd = (sd == 0.0f) ? 1.0f : sd;
            float v = (xc[f] - norm_mean[f]) / sd;
            v = fminf(fmaxf(v, -5.0f), 5.0f);
            u.us[f] = f2bf(v);
        }
        #pragma unroll
        for (int f = DIN; f < 31; ++f) u.us[f] = 0;
        u.us[31] = 0x3F80;   // 1.0 bf16 -> bias column
        int4* dst = reinterpret_cast<int4*>(xnB + ((size_t)b*NK + t)*32);
        dst[0] = u.v4[0]; dst[1] = u.v4[1]; dst[2] = u.v4[2]; dst[3] = u.v4[3];
        const bool msk = (xc[2] == 0.0f);
        outrel[((size_t)b*NK + t)*2 + 0] = r0;
        outrel[((size_t)b*NK + t)*2 + 1] = r1;
        outmask[(size_t)b*NK + t] = msk ? 1.0f : 0.0f;
    }
}

// ---- kernel 2: transposed register MLP; EVERYTHING loop-invariant lives in LDS,
// per-iteration bases are made opaque (defeats LICM hoist->spill, R8/R9's 0.5GB
// phantom FETCH), sched_barrier(0) fences bound the scheduler's register window.
__global__ __launch_bounds__(256, 1) void mlp_kernel(
    const float* __restrict__ b1, const float* __restrict__ b2,
    const float* __restrict__ ln1g, const float* __restrict__ ln1b,
    const float* __restrict__ ln2g, const float* __restrict__ ln2b,
    const ushort* __restrict__ Wembc, const ushort* __restrict__ W1c,
    const ushort* __restrict__ W2c, const ushort* __restrict__ xnB,
    const float* __restrict__ outmask, float* __restrict__ out)
{
    __shared__ __align__(16) ushort s_wemb[4096];    //  8 KB
    __shared__ __align__(16) ushort s_w1[32768];     // 64 KB
    __shared__ __align__(16) ushort s_w2[32768];     // 64 KB
    __shared__ __align__(16) float  s_bias[896];     // 3.5 KB
    // total ~140 KB -> 1 block/CU

    const int t = threadIdx.x;
    {
        // R10 BUG FIX: 256 threads must stage all 512 int4s of s_wemb (2 each)
        ((int4*)s_wemb)[t]       = ((const int4*)Wembc)[t];
        ((int4*)s_wemb)[t + 256] = ((const int4*)Wembc)[t + 256];
        const int4* g1 = (const int4*)W1c;  int4* d1 = (int4*)s_w1;
        const int4* g2 = (const int4*)W2c;  int4* d2 = (int4*)s_w2;
        #pragma unroll
        for (int j = 0; j < 16; ++j) { d1[j*256 + t] = g1[j*256 + t];
                                       d2[j*256 + t] = g2[j*256 + t]; }
        s_bias[t] = b1[t];                                   // [0,256)
        if (t < 128) {
            s_bias[256 + t] = b2[t];
            s_bias[384 + t] = ln1g[t];
            s_bias[512 + t] = ln1b[t];
            s_bias[640 + t] = ln2g[t];
            s_bias[768 + t] = ln2b[t];
        }
    }
    __syncthreads();

    const int wave = t >> 6, lane = t & 63;
    const int lr = lane & 15, lg = lane >> 4;
    const int m0 = wave * 16;

    const f32x4 zero = {0.f, 0.f, 0.f, 0.f};

    for (int it = 0; it < 16; ++it) {
        // ---- opaque bases: nothing below can be LICM'd or pipelined across iters ----
        unsigned o_we = 0, o_w1 = 0, o_w2 = 0, o_sb = 0;
        int itv = it;
        asm volatile("" : "+v"(o_we), "+v"(o_w1), "+v"(o_w2), "+v"(o_sb), "+v"(itv));
        const ushort* wep = s_wemb + o_we;
        const ushort* w1p = s_w1 + o_w1;
        const ushort* w2p = s_w2 + o_w2;
        const float*  sbp = s_bias + o_sb;
        const int b = blockIdx.x*16 + itv;

        // ---- G1 (swapped): h1T = Wemb @ xn^T ; bias folded via xn col31=1 ----
        const short8 xA = *(const short8*)(xnB + ((size_t)b*NK + m0 + lr)*32 + 8*lg);
        f32x4 h1[8];
        #pragma unroll
        for (int nt = 0; nt < 8; ++nt) {
            const short8 w = *(const short8*)(wep + nt*512 + lane*8);
            h1[nt] = mfma32(w, xA, zero);
        }
        __builtin_amdgcn_sched_barrier(0);

        // ---- LN1: relu + stats over n (lane-local 32 + 2 shuffles) ----
        float ps = 0.f, pq = 0.f;
        #pragma unroll
        for (int nt = 0; nt < 8; ++nt)
            #pragma unroll
            for (int r = 0; r < 4; ++r) {
                float a = fmaxf(h1[nt][r], 0.f); h1[nt][r] = a; ps += a; pq += a*a;
            }
        #pragma unroll
        for (int m = 16; m <= 32; m <<= 1) {
            ps += __shfl_xor(ps, m, 64); pq += __shfl_xor(pq, m, 64);
        }
        const float mu = ps*(1.f/128.f);
        const float rs = rsqrtf(pq*(1.f/128.f) - mu*mu + 1e-5f);

        // ---- affine + pack to bf16 (these ARE the G2 B-fragments) ----
        short4v h1p[8];
        #pragma unroll
        for (int nt = 0; nt < 8; ++nt) {
            const float4 g  = *(const float4*)(sbp + 384 + nt*16 + 4*lg);
            const float4 bb = *(const float4*)(sbp + 512 + nt*16 + 4*lg);
            const float gr[4] = {g.x, g.y, g.z, g.w};
            const float br[4] = {bb.x, bb.y, bb.z, bb.w};
            #pragma unroll
            for (int r = 0; r < 4; ++r)
                h1p[nt][r] = (short)f2bf((h1[nt][r]-mu)*rs*gr[r] + br[r]);
        }
        __builtin_amdgcn_sched_barrier(0);

        // ---- G2 (chunks of 4 n2-tiles) feeding G3 accumulation ----
        f32x4 acc3[8];
        #pragma unroll
        for (int nt3 = 0; nt3 < 8; ++nt3) {
            const float4 bb = *(const float4*)(sbp + 256 + nt3*16 + 4*lg);
            acc3[nt3] = f32x4{bb.x, bb.y, bb.z, bb.w};
        }
        #pragma unroll
        for (int ck = 0; ck < 4; ++ck) {
            short4v h2p[4];
            #pragma unroll
            for (int j = 0; j < 4; ++j) {
                const int nt2 = ck*4 + j;
                const float4 bb = *(const float4*)(sbp + nt2*16 + 4*lg);
                f32x4 a2 = f32x4{bb.x, bb.y, bb.z, bb.w};
                #pragma unroll
                for (int kt = 0; kt < 8; ++kt) {
                    const short4v w = *(const short4v*)(w1p + (nt2*8 + kt)*256 + lane*4);
                    a2 = mfma16(w, h1p[kt], a2);
                }
                #pragma unroll
                for (int r = 0; r < 4; ++r)
                    h2p[j][r] = (short)f2bf(fmaxf(a2[r], 0.f));
            }
            __builtin_amdgcn_sched_barrier(0);
            #pragma unroll
            for (int nt3 = 0; nt3 < 8; ++nt3)
                #pragma unroll
                for (int j = 0; j < 4; ++j) {
                    const short4v w = *(const short4v*)(w2p + (nt3*16 + ck*4 + j)*256 + lane*4);
                    acc3[nt3] = mfma16(w, h2p[j], acc3[nt3]);
                }
            __builtin_amdgcn_sched_barrier(0);
        }

        // ---- residual + LN2 stats (T layout) ----
        const float keep = 1.f - outmask[(size_t)b*NK + m0 + lr];
        ps = 0.f; pq = 0.f;
        #pragma unroll
        for (int nt = 0; nt < 8; ++nt)
            #pragma unroll
            for (int r = 0; r < 4; ++r) {
                const float q = bf2f((ushort)h1p[nt][r]) + fmaxf(acc3[nt][r], 0.f);
                acc3[nt][r] = q; ps += q; pq += q*q;
            }
        #pragma unroll
        for (int m = 16; m <= 32; m <<= 1) {
            ps += __shfl_xor(ps, m, 64); pq += __shfl_xor(pq, m, 64);
        }
        const float m2 = ps*(1.f/128.f);
        const float r2 = rsqrtf(pq*(1.f/128.f) - m2*m2 + 1e-5f);

        // ---- LN2 affine + mask + store (full 64B line per (row,nt)) ----
        #pragma unroll
        for (int nt = 0; nt < 8; ++nt) {
            const float4 g  = *(const float4*)(sbp + 640 + nt*16 + 4*lg);
            const float4 bb = *(const float4*)(sbp + 768 + nt*16 + 4*lg);
            float4 o;
            o.x = ((acc3[nt][0]-m2)*r2*g.x + bb.x)*keep;
            o.y = ((acc3[nt][1]-m2)*r2*g.y + bb.y)*keep;
            o.z = ((acc3[nt][2]-m2)*r2*g.z + bb.z)*keep;
            o.w = ((acc3[nt][3]-m2)*r2*g.w + bb.w)*keep;
            *(float4*)(out + ((size_t)b*NK + m0 + lr)*DM + nt*16 + 4*lg) = o;
        }
        __builtin_amdgcn_sched_barrier(0);
    }
}

extern "C" void kernel_launch(void* const* d_in, const int* in_sizes, int n_in,
                              void* d_out, int out_size, void* d_ws, size_t ws_size,
                              hipStream_t stream) {
    const float* x        = (const float*)d_in[0];
    const int*   idxs     = (const int*)  d_in[1];
    const float* origin   = (const float*)d_in[2];
    const float* direction= (const float*)d_in[3];
    const float* ncount   = (const float*)d_in[4];
    const float* nmean    = (const float*)d_in[5];
    const float* nsq      = (const float*)d_in[6];
    const float* W_emb    = (const float*)d_in[7];
    const float* b_emb    = (const float*)d_in[8];
    const float* ln1g     = (const float*)d_in[9];
    const float* ln1b     = (const float*)d_in[10];
    const float* W1       = (const float*)d_in[11];
    const float* b1       = (const float*)d_in[12];
    const float* W2       = (const float*)d_in[13];
    const float* b2       = (const float*)d_in[14];
    const float* ln2g     = (const float*)d_in[15];
    const float* ln2b     = (const float*)d_in[16];

    float* out     = (float*)d_out;
    float* outrel  = out    + (size_t)NB*NK*DM;
    float* outmask = outrel + (size_t)NB*NK*2;

    ushort* Wembc = (ushort*)d_ws;              // 4096
    ushort* W1c   = Wembc + 4096;               // 32768
    ushort* W2c   = W1c   + 32768;              // 32768
    ushort* xnB   = W2c   + 32768;              // 4096*64*32 (16 MB)

    convert_weights<<<128, 256, 0, stream>>>(W_emb, b_emb, W1, W2, Wembc, W1c, W2c);
    select_kernel<<<NB, 256, 0, stream>>>(x, idxs, origin, direction, ncount,
        nmean, nsq, xnB, outrel, outmask);
    mlp_kernel<<<256, 256, 0, stream>>>(b1, b2, ln1g, ln1b, ln2g, ln2b,
        Wembc, W1c, W2c, xnB, outmask, out);
}